// Round 1
// 2165.080 us; speedup vs baseline: 1.3716x; 1.3716x over previous
//
#include <hip/hip_runtime.h>
#include <hip/hip_bf16.h>

// Problem constants (hardcoded in the reference module)
#define P 4
#define NN 100000
#define MM 50000
#define EE 400000
#define DD 128
#define ROWS 32

typedef __attribute__((ext_vector_type(8))) short bf16x8;   // 8 bf16 in 4 VGPRs
typedef __attribute__((ext_vector_type(4))) float f32x4;    // MFMA accumulator

__device__ inline unsigned short bf16u(float x) {
    __hip_bfloat16 h = __float2bfloat16(x);                 // RNE
    return __builtin_bit_cast(unsigned short, h);
}
__device__ inline float bf16f(unsigned short u) {
    return __builtin_bit_cast(float, (unsigned)u << 16);
}

// ---------------------------------------------------------------------------
// K1: per-(s,d) pair: count original-dst degree (mean weights). One atomic/edge.
__global__ __launch_bounds__(256) void k_count(const int* __restrict__ edge_dst,
                                               int* __restrict__ deg_orig) {
    int i = blockIdx.x * 256 + threadIdx.x;
    if (i >= P * P * EE) return;
    int pair = i / EE;
    atomicAdd(&deg_orig[pair * MM + edge_dst[i]], 1);
}

// K1b: derive merged-row counts from deg_orig (replaces 6.4M per-edge atomics
//      with 800K per-row atomics) and self-term counts.
__global__ __launch_bounds__(256) void k_derive(const int* __restrict__ merge,
                                                const int* __restrict__ deg_orig,
                                                int* __restrict__ cnt_n,
                                                int* __restrict__ cnt_s) {
    int i = blockIdx.x * 256 + threadIdx.x;
    if (i >= P * P * MM) return;
    int pair = i / MM;
    int r = i - pair * MM;
    int s = pair >> 2, d = pair & 3;
    int m = (s == d) ? r : merge[i];
    atomicAdd(&cnt_n[pair * MM + m], deg_orig[i]);
    atomicAdd(&cnt_s[pair * MM + m], 1);
}

// ---------------------------------------------------------------------------
// K2: exclusive scan of cnt -> row_start; then zero cnt so it can be reused
//     as the fill cursor. blocks 0..15: neigh, 16..31: self.
__global__ __launch_bounds__(1024) void k_scan(int* __restrict__ cnt_n,
                                               int* __restrict__ rs_n,
                                               int* __restrict__ cnt_s,
                                               int* __restrict__ rs_s) {
    int which = blockIdx.x >> 4;
    int pair = blockIdx.x & 15;
    int* cnt = (which ? cnt_s : cnt_n) + pair * MM;
    int* rs  = (which ? rs_s : rs_n) + pair * (MM + 1);
    __shared__ int sh[1024];
    int running = 0;
    for (int base = 0; base < MM; base += 1024) {
        int i = base + (int)threadIdx.x;
        int v = (i < MM) ? cnt[i] : 0;
        sh[threadIdx.x] = v;
        __syncthreads();
        for (int off = 1; off < 1024; off <<= 1) {
            int t = (threadIdx.x >= (unsigned)off) ? sh[threadIdx.x - off] : 0;
            __syncthreads();
            sh[threadIdx.x] += t;
            __syncthreads();
        }
        int incl = sh[threadIdx.x];
        if (i < MM) rs[i] = running + incl - v;   // exclusive
        running += sh[1023];
        __syncthreads();
    }
    if (threadIdx.x == 0) rs[MM] = running;
    __syncthreads();
    for (int i = threadIdx.x; i < MM; i += 1024) cnt[i] = 0;   // reuse as cursor
}

// ---------------------------------------------------------------------------
// K3: counting-sort neigh edges into merged-dst CSR with mean weights.
__global__ __launch_bounds__(256) void k_fill(const int* __restrict__ edge_src,
                                              const int* __restrict__ edge_dst,
                                              const int* __restrict__ merge,
                                              const int* __restrict__ deg_orig,
                                              const int* __restrict__ rs_n,
                                              int* __restrict__ cur_n,
                                              int* __restrict__ csn_src,
                                              float* __restrict__ csn_w) {
    int i = blockIdx.x * 256 + threadIdx.x;
    if (i >= P * P * EE) return;
    int pair = i / EE;
    int s = pair >> 2, d = pair & 3;
    int od = edge_dst[i];
    int m = (s == d) ? od : merge[pair * MM + od];
    float w = 1.0f / fmaxf((float)deg_orig[pair * MM + od], 1.0f);
    int pos = rs_n[pair * (MM + 1) + m] + atomicAdd(&cur_n[pair * MM + m], 1);
    csn_src[pair * EE + pos] = edge_src[i];
    csn_w[pair * EE + pos] = w;
}

// K3b: self-term CSR (row r of x[s][:M] contributes to merged row m).
__global__ __launch_bounds__(256) void k_fill_self(const int* __restrict__ merge,
                                                   const int* __restrict__ rs_s,
                                                   int* __restrict__ cur_s,
                                                   int* __restrict__ css) {
    int i = blockIdx.x * 256 + threadIdx.x;
    if (i >= P * P * MM) return;
    int pair = i / MM;
    int r = i - pair * MM;
    int s = pair >> 2, d = pair & 3;
    int m = (s == d) ? r : merge[i];
    int pos = rs_s[pair * (MM + 1) + m] + atomicAdd(&cur_s[pair * MM + m], 1);
    css[pair * MM + pos] = r;
}

// ---------------------------------------------------------------------------
// K3c: split weights into hi/lo bf16, packed fragment-ready:
//      Bpk[s][hl(2)][kchunk(32)][col(128)][8k]  (chunks 0-15 = W_self rows,
//      16-31 = W_neigh rows). 512 KB total; overlaid on dead deg_orig space.
__global__ __launch_bounds__(256) void k_pack_w(const float* __restrict__ Ws,
                                                const float* __restrict__ Wn,
                                                unsigned short* __restrict__ Bpk) {
    int t = blockIdx.x * 256 + threadIdx.x;     // 4s * 32c * 128col = 16384
    if (t >= 4 * 32 * 128) return;
    int s = t >> 12;
    int rem = t & 4095;                         // c*128 + col
    int c = rem >> 7, col = rem & 127;
    const float* W = (c < 16) ? (Ws + (size_t)s * DD * DD + (c * 8) * DD + col)
                              : (Wn + (size_t)s * DD * DD + ((c - 16) * 8) * DD + col);
    size_t ohi = ((size_t)(s * 2 + 0) * 4096 + rem) * 8;
    size_t olo = ((size_t)(s * 2 + 1) * 4096 + rem) * 8;
    #pragma unroll
    for (int j = 0; j < 8; ++j) {
        float v = W[(size_t)j * DD];
        unsigned short h = bf16u(v);
        unsigned short l = bf16u(v - bf16f(h));
        Bpk[ohi + j] = h;
        Bpk[olo + j] = l;
    }
}

// ---------------------------------------------------------------------------
// K4: fused per-d kernel. Gather (fp32) -> hi/lo bf16 split into swizzled LDS
//     -> 16x16x32 bf16 MFMA GEMM (hi*hi + lo*hi + hi*lo, fp32 accum).
//     LDS 32 KB -> 5 blocks/CU.
__global__ __launch_bounds__(256, 5) void k_fused(const float* __restrict__ x_all,
                                                  const float* __restrict__ b_all,
                                                  const int* __restrict__ rs_n_all,
                                                  const int* __restrict__ csn_src_all,
                                                  const float* __restrict__ csn_w_all,
                                                  const int* __restrict__ rs_s_all,
                                                  const int* __restrict__ css_all,
                                                  const unsigned short* __restrict__ Bpk,
                                                  float* __restrict__ out) {
    int d = blockIdx.y;
    int m0 = blockIdx.x * ROWS;
    int tid = threadIdx.x;
    int lane = tid & 63, wv = tid >> 6;
    int l15 = lane & 15, kg = lane >> 4;

    // A_hi [32 rows][256 k] bf16 @0, A_lo @16384. Row stride 512 B.
    // XOR-swizzle byte ^= ((row&7)<<4) to break the 512B-stride bank conflict.
    __shared__ char lds[32768];

    f32x4 acc[2][2];
    f32x4 zero = {0.f, 0.f, 0.f, 0.f};
    acc[0][0] = zero; acc[0][1] = zero; acc[1][0] = zero; acc[1][1] = zero;

    for (int s = 0; s < P; ++s) {
        int pair = s * P + d;
        const float* x   = x_all + (size_t)s * NN * DD;
        const int* rsn   = rs_n_all + (size_t)pair * (MM + 1);
        const int* csn   = csn_src_all + (size_t)pair * EE;
        const float* cw  = csn_w_all + (size_t)pair * EE;
        const int* rss   = rs_s_all + (size_t)pair * (MM + 1);
        const int* css   = css_all + (size_t)pair * MM;

        // ---- gather: wave wv handles rows wv, wv+4, ... lane covers k {2l,2l+1}
        for (int r = wv; r < ROWS; r += 4) {
            int m = m0 + r;
            float sx = 0.f, sy = 0.f, nx = 0.f, ny = 0.f;
            if (m < MM) {
                // self-scatter sum (avg 1 row)
                int e0 = rss[m], e1 = rss[m + 1];
                for (int e = e0; e < e1; ++e) {
                    float2 v = ((const float2*)(x + (size_t)css[e] * DD))[lane];
                    sx += v.x; sy += v.y;
                }
                // weighted neigh sum (avg 8 rows), 4-wide unroll for MLP
                e0 = rsn[m]; e1 = rsn[m + 1];
                int e = e0;
                for (; e + 4 <= e1; e += 4) {
                    int j0 = csn[e], j1 = csn[e + 1], j2 = csn[e + 2], j3 = csn[e + 3];
                    float w0 = cw[e], w1 = cw[e + 1], w2 = cw[e + 2], w3 = cw[e + 3];
                    float2 v0 = ((const float2*)(x + (size_t)j0 * DD))[lane];
                    float2 v1 = ((const float2*)(x + (size_t)j1 * DD))[lane];
                    float2 v2 = ((const float2*)(x + (size_t)j2 * DD))[lane];
                    float2 v3 = ((const float2*)(x + (size_t)j3 * DD))[lane];
                    nx += w0 * v0.x + w1 * v1.x + w2 * v2.x + w3 * v3.x;
                    ny += w0 * v0.y + w1 * v1.y + w2 * v2.y + w3 * v3.y;
                }
                for (; e < e1; ++e) {
                    float w = cw[e];
                    float2 v = ((const float2*)(x + (size_t)csn[e] * DD))[lane];
                    nx += w * v.x; ny += w * v.y;
                }
            }
            // hi/lo bf16 split -> swizzled LDS. self half k[0,128), neigh k[128,256)
            int xr = (r & 7) << 4;
            int rbase = r * 512;
            unsigned short hx = bf16u(sx), hy = bf16u(sy);
            unsigned short lx = bf16u(sx - bf16f(hx)), ly = bf16u(sy - bf16f(hy));
            *(unsigned*)(lds + rbase + ((4 * lane) ^ xr))         = hx | ((unsigned)hy << 16);
            *(unsigned*)(lds + 16384 + rbase + ((4 * lane) ^ xr)) = lx | ((unsigned)ly << 16);
            hx = bf16u(nx); hy = bf16u(ny);
            lx = bf16u(nx - bf16f(hx)); ly = bf16u(ny - bf16f(hy));
            *(unsigned*)(lds + rbase + ((256 + 4 * lane) ^ xr))         = hx | ((unsigned)hy << 16);
            *(unsigned*)(lds + 16384 + rbase + ((256 + 4 * lane) ^ xr)) = lx | ((unsigned)ly << 16);
        }
        __syncthreads();

        // ---- MFMA GEMM: acc[32][128] += A[32][256] @ [Ws[s]; Wn[s]]
        // wave wv -> cols [wv*32, wv*32+32); row tiles {0-15, 16-31}.
        {
            int row0 = l15, row1 = 16 + l15;
            int xr = (l15 & 7) << 4;                 // same for row0/row1
            const bf16x8* Bh = (const bf16x8*)(Bpk + (size_t)(s * 2 + 0) * 4096 * 8);
            const bf16x8* Bl = (const bf16x8*)(Bpk + (size_t)(s * 2 + 1) * 4096 * 8);
            int colbase = wv * 32 + l15;
            #pragma unroll
            for (int kk = 0; kk < 8; ++kk) {
                int c = kk * 4 + kg;                 // 16B chunk index in row
                int co = (c * 16) ^ xr;
                bf16x8 ah0 = *(const bf16x8*)(lds + row0 * 512 + co);
                bf16x8 ah1 = *(const bf16x8*)(lds + row1 * 512 + co);
                bf16x8 al0 = *(const bf16x8*)(lds + 16384 + row0 * 512 + co);
                bf16x8 al1 = *(const bf16x8*)(lds + 16384 + row1 * 512 + co);
                size_t bo = (size_t)c * 128 + colbase;
                bf16x8 bh0 = Bh[bo];
                bf16x8 bh1 = Bh[bo + 16];
                bf16x8 bl0 = Bl[bo];
                bf16x8 bl1 = Bl[bo + 16];
                acc[0][0] = __builtin_amdgcn_mfma_f32_16x16x32_bf16(ah0, bh0, acc[0][0], 0, 0, 0);
                acc[0][1] = __builtin_amdgcn_mfma_f32_16x16x32_bf16(ah0, bh1, acc[0][1], 0, 0, 0);
                acc[1][0] = __builtin_amdgcn_mfma_f32_16x16x32_bf16(ah1, bh0, acc[1][0], 0, 0, 0);
                acc[1][1] = __builtin_amdgcn_mfma_f32_16x16x32_bf16(ah1, bh1, acc[1][1], 0, 0, 0);
                acc[0][0] = __builtin_amdgcn_mfma_f32_16x16x32_bf16(al0, bh0, acc[0][0], 0, 0, 0);
                acc[0][1] = __builtin_amdgcn_mfma_f32_16x16x32_bf16(al0, bh1, acc[0][1], 0, 0, 0);
                acc[1][0] = __builtin_amdgcn_mfma_f32_16x16x32_bf16(al1, bh0, acc[1][0], 0, 0, 0);
                acc[1][1] = __builtin_amdgcn_mfma_f32_16x16x32_bf16(al1, bh1, acc[1][1], 0, 0, 0);
                acc[0][0] = __builtin_amdgcn_mfma_f32_16x16x32_bf16(ah0, bl0, acc[0][0], 0, 0, 0);
                acc[0][1] = __builtin_amdgcn_mfma_f32_16x16x32_bf16(ah0, bl1, acc[0][1], 0, 0, 0);
                acc[1][0] = __builtin_amdgcn_mfma_f32_16x16x32_bf16(ah1, bl0, acc[1][0], 0, 0, 0);
                acc[1][1] = __builtin_amdgcn_mfma_f32_16x16x32_bf16(ah1, bl1, acc[1][1], 0, 0, 0);
            }
        }

        // ---- bias: each contributing source row brings one b[s]
        {
            float bv0 = b_all[(size_t)s * DD + wv * 32 + l15];
            float bv1 = b_all[(size_t)s * DD + wv * 32 + 16 + l15];
            #pragma unroll
            for (int rt = 0; rt < 2; ++rt) {
                int mb = m0 + rt * 16 + kg * 4;
                #pragma unroll
                for (int r = 0; r < 4; ++r) {
                    int m = mb + r;
                    if (m < MM) {
                        float cf = (float)(rss[m + 1] - rss[m]);
                        acc[rt][0][r] += cf * bv0;
                        acc[rt][1][r] += cf * bv1;
                    }
                }
            }
        }
        __syncthreads();   // before next s overwrites LDS
    }

    // ---- store. D layout: col = lane&15 (+tile), row = (lane>>4)*4 + reg (+tile)
    float* outd = out + (size_t)d * MM * DD;
    #pragma unroll
    for (int rt = 0; rt < 2; ++rt) {
        #pragma unroll
        for (int r = 0; r < 4; ++r) {
            int m = m0 + rt * 16 + kg * 4 + r;
            if (m >= MM) continue;
            float* o = outd + (size_t)m * DD + wv * 32 + l15;
            o[0]  = acc[rt][0][r];
            o[16] = acc[rt][1][r];
        }
    }
}

// ---------------------------------------------------------------------------
extern "C" void kernel_launch(void* const* d_in, const int* in_sizes, int n_in,
                              void* d_out, int out_size, void* d_ws, size_t ws_size,
                              hipStream_t stream) {
    const float* x     = (const float*)d_in[0];   // [P][N][D]
    const float* Ws    = (const float*)d_in[1];   // [P][D][D]
    const float* Wn    = (const float*)d_in[2];   // [P][D][D]
    const float* b     = (const float*)d_in[3];   // [P][D]
    const int*   esrc  = (const int*)d_in[4];     // [P][P][E]
    const int*   edst  = (const int*)d_in[5];     // [P][P][E]
    const int*   merge = (const int*)d_in[6];     // [P][P][M]
    float* out = (float*)d_out;                   // [P][M][D]

    // workspace layout (ints unless noted), ~70.4 MB total:
    int* deg_orig = (int*)d_ws;                   // [16*M]; dead after k_fill ->
                                                  //   reused as Bpk (512 KB)
    int* cnt_n    = deg_orig + 16 * MM;           // [16*M] counts -> cursor after scan
    int* cnt_s    = cnt_n + 16 * MM;              // [16*M] counts -> cursor after scan
    int* rs_n     = cnt_s + 16 * MM;              // [16*(M+1)]
    int* rs_s     = rs_n + 16 * (MM + 1);         // [16*(M+1)]
    int* csn_src  = rs_s + 16 * (MM + 1);         // [16*E]
    float* csn_w  = (float*)(csn_src + 16 * EE);  // [16*E]
    int* css      = (int*)(csn_w + 16 * EE);      // [16*M]
    unsigned short* Bpk = (unsigned short*)d_ws;  // overlay on deg_orig

    hipMemsetAsync(d_ws, 0, sizeof(int) * (size_t)16 * MM * 3, stream);  // deg+cnt_n+cnt_s

    int eblocks = (P * P * EE + 255) / 256;       // 25000
    int mblocks16 = (P * P * MM + 255) / 256;     // 3125
    k_count<<<eblocks, 256, 0, stream>>>(edst, deg_orig);
    k_derive<<<mblocks16, 256, 0, stream>>>(merge, deg_orig, cnt_n, cnt_s);
    k_scan<<<32, 1024, 0, stream>>>(cnt_n, rs_n, cnt_s, rs_s);
    k_fill<<<eblocks, 256, 0, stream>>>(esrc, edst, merge, deg_orig, rs_n, cnt_n, csn_src, csn_w);
    k_fill_self<<<mblocks16, 256, 0, stream>>>(merge, rs_s, cnt_s, css);
    k_pack_w<<<64, 256, 0, stream>>>(Ws, Wn, Bpk);  // overwrites deg_orig (dead)

    dim3 gfused((MM + ROWS - 1) / ROWS, P);       // (1563, 4)
    k_fused<<<gfused, 256, 0, stream>>>(x, b, rs_n, csn_src, csn_w, rs_s, css, Bpk, out);
}